// Round 11
// baseline (4804.314 us; speedup 1.0000x reference)
//
#include <hip/hip_runtime.h>

#define TT 2048
#define HD 64

// One wave = one batch row, BOTH layers. Lane j owns unit j of L0 and L1.
// All weights live in VGPRs (fp16-packed, 384 regs). h crosses lanes through a
// per-wave 256B LDS slice: write 64xb16 (2-lane/bank = free), read back as
// same-address broadcast ds_read_b128 (conflict-free). NO barriers anywhere —
// all ordering is same-wave s_waitcnt lgkmcnt(0).
//
// Gate pre-scales folded into weights/biases:
//   sigmoid gates (i,f,o): t = -log2(e)*z   -> sigma(z) = rcp(1+exp2(t))
//   tanh gate (g):         t = -2*log2(e)*z -> tanh(z)  = 2*rcp(1+exp2(t)) - 1
#define SIC -1.4426950408889634f
#define SGC -2.8853900817779268f

#if __has_builtin(__builtin_amdgcn_exp2f)
#define EXP2F(x) __builtin_amdgcn_exp2f(x)
#else
#define EXP2F(x) __expf(0.69314718055994531f * (x))
#endif
#if __has_builtin(__builtin_amdgcn_rcpf)
#define RCPF(x) __builtin_amdgcn_rcpf(x)
#else
#define RCPF(x) (1.0f / (x))
#endif

__device__ __forceinline__ float rcp1p(float t) { return RCPF(1.0f + EXP2F(t)); }

typedef _Float16 v2h __attribute__((ext_vector_type(2)));

// v_dot2_f32_f16: 2 fp16 products + f32 accumulate in ONE VALU instr.
#if __has_builtin(__builtin_amdgcn_fdot2)
#define FDOT2(a, b, c) __builtin_amdgcn_fdot2((a), (b), (c), false)
#else
#define FDOT2(a, b, c) __fmaf_rn((float)(a)[1], (float)(b)[1], __fmaf_rn((float)(a)[0], (float)(b)[0], (c)))
#endif

static __device__ __forceinline__ v2h bch(float f) { return __builtin_bit_cast(v2h, f); }
static __device__ __forceinline__ v2h packw(float a, float b, float s) {
    v2h r; r[0] = (_Float16)(a * s); r[1] = (_Float16)(b * s); return r;
}

// Same-wave LDS ordering fence (write -> visible to own reads).
#define LGKM0() asm volatile("s_waitcnt lgkmcnt(0)" ::: "memory")

// Quarter-dot: 4 broadcast ds_read_b128 (16 v2h = 32 K-values) x 4 gates.
// W[g][PB+p] must hold K-pair (PB+p) -> weights and h walk K together.
// Fully unrolled constant indices -> arrays stay in registers (rule #20).
#define DOTQ(W, PB, HP, A0, A1, A2, A3)                                        \
{                                                                              \
    const float4 q0_ = *(const float4*)((HP));                                 \
    const float4 q1_ = *(const float4*)((HP) + 16);                            \
    const float4 q2_ = *(const float4*)((HP) + 32);                            \
    const float4 q3_ = *(const float4*)((HP) + 48);                            \
    v2h h_[16];                                                                \
    h_[0]  = bch(q0_.x); h_[1]  = bch(q0_.y); h_[2]  = bch(q0_.z); h_[3]  = bch(q0_.w); \
    h_[4]  = bch(q1_.x); h_[5]  = bch(q1_.y); h_[6]  = bch(q1_.z); h_[7]  = bch(q1_.w); \
    h_[8]  = bch(q2_.x); h_[9]  = bch(q2_.y); h_[10] = bch(q2_.z); h_[11] = bch(q2_.w); \
    h_[12] = bch(q3_.x); h_[13] = bch(q3_.y); h_[14] = bch(q3_.z); h_[15] = bch(q3_.w); \
    _Pragma("unroll")                                                          \
    for (int p_ = 0; p_ < 16; ++p_) {                                          \
        A0 = FDOT2(W[0][(PB) + p_], h_[p_], A0);                               \
        A1 = FDOT2(W[1][(PB) + p_], h_[p_], A1);                               \
        A2 = FDOT2(W[2][(PB) + p_], h_[p_], A2);                               \
        A3 = FDOT2(W[3][(PB) + p_], h_[p_], A3);                               \
    }                                                                          \
}

// Block = 256 threads = 4 independent waves (one row each), NO __syncthreads
// in the loop. Grid 256 blocks -> 1024 waves = 1 wave per SIMD chip-wide.
// launch_bounds(256,1): 1 wave/EU -> VGPR budget up to 512 (weights need 384).
__global__ __launch_bounds__(256, 1)
void lstm2_kernel(const float* __restrict__ x,
                  const float* __restrict__ Wih0,
                  const float* __restrict__ Whh0,
                  const float* __restrict__ bih0,
                  const float* __restrict__ bhh0,
                  const float* __restrict__ Wih1,
                  const float* __restrict__ Whh1,
                  const float* __restrict__ bih1,
                  const float* __restrict__ bhh1,
                  const float* __restrict__ fcW,
                  const float* __restrict__ fcb,
                  float* __restrict__ out)
{
    __shared__ __align__(16) char arena[4 * 256];   // per-wave: h1[128B] + h2[128B]

    const int tid  = threadIdx.x;
    const int wid  = tid >> 6;
    const int lane = tid & 63;                      // unit j for both layers
    const int row  = blockIdx.x * 4 + wid;

    char* const hb  = arena + (wid << 8);           // h1 buffer
    char* const h2b = hb + 128;                     // h2 buffer

    // ---- weights: 384 fp16-pair VGPRs, gate-prescaled at pack ----
    v2h wl0[4][32];   // L0: Whh0 row (g*64+lane), K=64
    v2h wlA[4][32];   // L1: Wih1 row (h1 half),   K=64
    v2h wlB[4][32];   // L1: Whh1 row (h2 half),   K=64
#pragma unroll
    for (int g = 0; g < 4; ++g) {
        const float sc = (g == 2) ? SGC : SIC;
        const float* w0 = Whh0 + (g * HD + lane) * HD;
        const float* wa = Wih1 + (g * HD + lane) * HD;
        const float* wb = Whh1 + (g * HD + lane) * HD;
#pragma unroll
        for (int p = 0; p < 32; ++p) {
            wl0[g][p] = packw(w0[2 * p], w0[2 * p + 1], sc);
            wlA[g][p] = packw(wa[2 * p], wa[2 * p + 1], sc);
            wlB[g][p] = packw(wb[2 * p], wb[2 * p + 1], sc);
        }
    }

    // biases / x-weights (f32, pre-scaled)
    const float b00 = (bih0[0 * HD + lane] + bhh0[0 * HD + lane]) * SIC;
    const float b01 = (bih0[1 * HD + lane] + bhh0[1 * HD + lane]) * SIC;
    const float b02 = (bih0[2 * HD + lane] + bhh0[2 * HD + lane]) * SGC;
    const float b03 = (bih0[3 * HD + lane] + bhh0[3 * HD + lane]) * SIC;
    const float wx0 = Wih0[0 * HD + lane] * SIC;
    const float wx1 = Wih0[1 * HD + lane] * SIC;
    const float wx2 = Wih0[2 * HD + lane] * SGC;
    const float wx3 = Wih0[3 * HD + lane] * SIC;
    const float b10 = (bih1[0 * HD + lane] + bhh1[0 * HD + lane]) * SIC;
    const float b11 = (bih1[1 * HD + lane] + bhh1[1 * HD + lane]) * SIC;
    const float b12 = (bih1[2 * HD + lane] + bhh1[2 * HD + lane]) * SGC;
    const float b13 = (bih1[3 * HD + lane] + bhh1[3 * HD + lane]) * SIC;
    const float fcwj = fcW[lane];

    // zero own h buffers (same-wave ordering via LGKM0)
    *(_Float16*)(hb  + (lane << 1)) = (_Float16)0.f;
    *(_Float16*)(h2b + (lane << 1)) = (_Float16)0.f;
    LGKM0();

    // x stream: all lanes load the same address (broadcast via cache)
    const float* xp = x + row * TT;
    float xv = xp[0], xn = xp[1];

    float c1 = 0.f, c2 = 0.f, hlast = 0.f;

#pragma unroll 1
    for (int i = 0; i < TT; ++i) {
        const float xc = xv;
        xv = xn;
        xn = xp[(i + 2 < TT) ? (i + 2) : (TT - 1)];

        // ---- L0: gates = Whh0 . h1[i-1] + x*Wih0 + b  (seeded with x+bias) ----
        float a0 = __fmaf_rn(xc, wx0, b00);
        float a1 = __fmaf_rn(xc, wx1, b01);
        float a2 = __fmaf_rn(xc, wx2, b02);
        float a3 = __fmaf_rn(xc, wx3, b03);
        DOTQ(wl0, 0,  hb,      a0, a1, a2, a3)
        DOTQ(wl0, 16, hb + 64, a0, a1, a2, a3)

        // ---- L1 h2-half early: independent of L0's act -> hides trans latency ----
        float g0 = b10, g1 = b11, g2 = b12, g3 = b13;
        DOTQ(wlB, 0,  h2b,      g0, g1, g2, g3)
        DOTQ(wlB, 16, h2b + 64, g0, g1, g2, g3)

        // ---- L0 activations -> h1[i] ----
        const float iv = rcp1p(a0);
        const float fv = rcp1p(a1);
        const float gv = __fmaf_rn(2.f, rcp1p(a2), -1.f);
        const float ov = rcp1p(a3);
        c1 = __fmaf_rn(fv, c1, iv * gv);
        const float h1n = ov * __fmaf_rn(2.f, rcp1p(c1 * SGC), -1.f);
        *(_Float16*)(hb + (lane << 1)) = (_Float16)h1n;
        LGKM0();                       // h1[i] visible to own reads

        // ---- L1 h1-half: Wih1 . h1[i] ----
        DOTQ(wlA, 0,  hb,      g0, g1, g2, g3)
        DOTQ(wlA, 16, hb + 64, g0, g1, g2, g3)

        // ---- L1 activations -> h2[i] ----
        const float i2 = rcp1p(g0);
        const float f2 = rcp1p(g1);
        const float g2v = __fmaf_rn(2.f, rcp1p(g2), -1.f);
        const float o2 = rcp1p(g3);
        c2 = __fmaf_rn(f2, c2, i2 * g2v);
        hlast = o2 * __fmaf_rn(2.f, rcp1p(c2 * SGC), -1.f);
        *(_Float16*)(h2b + (lane << 1)) = (_Float16)hlast;
        LGKM0();                       // h2[i] visible before next step's reads
    }

    // ---- FC: out[row] = sum_j h2[T-1][j] * fcW[j] + fcb (wave reduce) ----
    float s = hlast * fcwj;
    s += __shfl_xor(s, 1, 64);
    s += __shfl_xor(s, 2, 64);
    s += __shfl_xor(s, 4, 64);
    s += __shfl_xor(s, 8, 64);
    s += __shfl_xor(s, 16, 64);
    s += __shfl_xor(s, 32, 64);
    if (lane == 0) out[row] = s + fcb[0];
}

extern "C" void kernel_launch(void* const* d_in, const int* in_sizes, int n_in,
                              void* d_out, int out_size, void* d_ws, size_t ws_size,
                              hipStream_t stream) {
    const float* x    = (const float*)d_in[0];
    const float* Wih0 = (const float*)d_in[1];
    const float* Whh0 = (const float*)d_in[2];
    const float* bih0 = (const float*)d_in[3];
    const float* bhh0 = (const float*)d_in[4];
    const float* Wih1 = (const float*)d_in[5];
    const float* Whh1 = (const float*)d_in[6];
    const float* bih1 = (const float*)d_in[7];
    const float* bhh1 = (const float*)d_in[8];
    const float* fcW  = (const float*)d_in[9];
    const float* fcb  = (const float*)d_in[10];
    float* out = (float*)d_out;

    lstm2_kernel<<<256, 256, 0, stream>>>(x, Wih0, Whh0, bih0, bhh0,
                                          Wih1, Whh1, bih1, bhh1,
                                          fcW, fcb, out);
}